// Round 2
// baseline (3222.842 us; speedup 1.0000x reference)
//
#include <hip/hip_runtime.h>
#include <math.h>

#define E_EDGES 1000000
#define CIN     11
#define H_DIM   64
#define MT      32          // edges per block tile
#define LN_EPS  1e-5f

typedef unsigned short u16;

__device__ __forceinline__ float bf2f(u16 u) {
    union { unsigned int i; float f; } v; v.i = ((unsigned int)u) << 16; return v.f;
}
__device__ __forceinline__ u16 f2bf(float f) {
    union { float f; unsigned int i; } v; v.f = f;
    unsigned int x = v.i;
    return (u16)((x + 0x7FFFu + ((x >> 16) & 1u)) >> 16);   // RNE
}

// feats LDS layout: [k][edge], row stride 36 floats (pad 32->36 keeps 16B align,
// spreads banks).

__device__ __forceinline__ void stash_feats(float* feats, int k, int el,
                                            float xv, float av, float bv,
                                            float cv, float dv) {
    feats[(k      ) * 36 + el] = xv;
    feats[(k +  64) * 36 + el] = fabsf(av - cv);
    feats[(k + 128) * 36 + el] = av + cv;
    feats[(k + 192) * 36 + el] = fabsf(bv - dv);
    feats[(k + 256) * 36 + el] = bv + dv;
}

// ---------------------------------------------------------------------------
// Layer 0: feats(E x 55) @ w0(55x64) + b0 -> LN -> ReLU -> xout (bf16)
// ---------------------------------------------------------------------------
__global__ __launch_bounds__(256) void layer0_kernel(
    const float* __restrict__ x, const int* __restrict__ nbr,
    const float* __restrict__ w0, const float* __restrict__ b0,
    const float* __restrict__ lng, const float* __restrict__ lnb,
    u16* __restrict__ xout)
{
    __shared__ float feats[55 * 36];   // 7.9 KB
    __shared__ float wlds[55 * 64];    // 14.1 KB
    const int t  = threadIdx.x;
    const int e0 = blockIdx.x * MT;

    for (int i = t; i < 55 * 64; i += 256) wlds[i] = w0[i];

    {   // gather: 8 threads per edge
        const int tid8 = t & 7;
        const int el   = t >> 3;
        const int e    = e0 + el;
        const int4 n   = *(const int4*)(nbr + 4ull * (unsigned)e);
        for (int c = tid8; c < CIN; c += 8) {
            const float xv = x[(size_t)e   * CIN + c];
            const float av = x[(size_t)n.x * CIN + c];
            const float bv = x[(size_t)n.y * CIN + c];
            const float cv = x[(size_t)n.z * CIN + c];
            const float dv = x[(size_t)n.w * CIN + c];
            feats[(0*CIN + c) * 36 + el] = xv;
            feats[(1*CIN + c) * 36 + el] = fabsf(av - cv);
            feats[(2*CIN + c) * 36 + el] = av + cv;
            feats[(3*CIN + c) * 36 + el] = fabsf(bv - dv);
            feats[(4*CIN + c) * 36 + el] = bv + dv;
        }
    }
    __syncthreads();

    const int cg = t & 15;   // channel group: 4 channels
    const int eg = t >> 4;   // edge group:    2 edges
    float acc[2][4] = {{0.f,0.f,0.f,0.f},{0.f,0.f,0.f,0.f}};
    #pragma unroll 5
    for (int k = 0; k < 55; ++k) {
        const float2 f = *(const float2*)&feats[k * 36 + eg * 2];
        const float4 w = *(const float4*)&wlds[k * 64 + cg * 4];
        acc[0][0] = fmaf(f.x, w.x, acc[0][0]);
        acc[0][1] = fmaf(f.x, w.y, acc[0][1]);
        acc[0][2] = fmaf(f.x, w.z, acc[0][2]);
        acc[0][3] = fmaf(f.x, w.w, acc[0][3]);
        acc[1][0] = fmaf(f.y, w.x, acc[1][0]);
        acc[1][1] = fmaf(f.y, w.y, acc[1][1]);
        acc[1][2] = fmaf(f.y, w.z, acc[1][2]);
        acc[1][3] = fmaf(f.y, w.w, acc[1][3]);
    }

    const int c = cg * 4;
    const float4 bv = *(const float4*)&b0[c];
    const float4 gv = *(const float4*)&lng[c];
    const float4 bt = *(const float4*)&lnb[c];
    #pragma unroll
    for (int j = 0; j < 2; ++j) {
        float h0 = acc[j][0] + bv.x;
        float h1 = acc[j][1] + bv.y;
        float h2 = acc[j][2] + bv.z;
        float h3 = acc[j][3] + bv.w;
        float s = h0 + h1 + h2 + h3;
        float q = h0*h0 + h1*h1 + h2*h2 + h3*h3;
        for (int m = 1; m < 16; m <<= 1) {   // LN reduce over 16 lanes (64 ch)
            s += __shfl_xor(s, m);
            q += __shfl_xor(q, m);
        }
        const float mu   = s * (1.f / 64.f);
        const float var  = q * (1.f / 64.f) - mu * mu;
        const float rinv = rsqrtf(var + LN_EPS);
        const size_t e   = (size_t)e0 + eg * 2 + j;
        ushort4 o;
        o.x = f2bf(fmaxf(fmaf((h0 - mu) * rinv, gv.x, bt.x), 0.f));
        o.y = f2bf(fmaxf(fmaf((h1 - mu) * rinv, gv.y, bt.y), 0.f));
        o.z = f2bf(fmaxf(fmaf((h2 - mu) * rinv, gv.z, bt.z), 0.f));
        o.w = f2bf(fmaxf(fmaf((h3 - mu) * rinv, gv.w, bt.w), 0.f));
        *(ushort4*)&xout[e * H_DIM + c] = o;
    }
}

// ---------------------------------------------------------------------------
// Layers 1..3: feats(E x 320) @ W(320x64) + b -> LN -> ReLU -> (+ residual)
// Activations in/out are bf16 (compute fp32).
// ---------------------------------------------------------------------------
__global__ __launch_bounds__(256) void layer_kernel(
    const u16* __restrict__ xin, const int* __restrict__ nbr,
    const float* __restrict__ w, const float* __restrict__ bias,
    const float* __restrict__ lng, const float* __restrict__ lnb,
    u16* __restrict__ xout)
{
    __shared__ float feats[320 * 36];  // 45 KB
    __shared__ float wlds[64 * 64];    // 16 KB (k-chunked W)
    const int t  = threadIdx.x;
    const int e0 = blockIdx.x * MT;

    {   // gather: 8 threads/edge, 8 channels each (2x ushort4)
        const int tid8 = t & 7;
        const int el   = t >> 3;
        const int e    = e0 + el;
        const int4 n   = *(const int4*)(nbr + 4ull * (unsigned)e);
        const u16* xr = xin + (size_t)e   * H_DIM;
        const u16* ar = xin + (size_t)n.x * H_DIM;
        const u16* br = xin + (size_t)n.y * H_DIM;
        const u16* cr = xin + (size_t)n.z * H_DIM;
        const u16* dr = xin + (size_t)n.w * H_DIM;
        #pragma unroll
        for (int h = 0; h < 2; ++h) {
            const int c = tid8 * 8 + h * 4;
            const ushort4 xv = *(const ushort4*)(xr + c);
            const ushort4 av = *(const ushort4*)(ar + c);
            const ushort4 bv = *(const ushort4*)(br + c);
            const ushort4 cv = *(const ushort4*)(cr + c);
            const ushort4 dv = *(const ushort4*)(dr + c);
            stash_feats(feats, c + 0, el, bf2f(xv.x), bf2f(av.x), bf2f(bv.x), bf2f(cv.x), bf2f(dv.x));
            stash_feats(feats, c + 1, el, bf2f(xv.y), bf2f(av.y), bf2f(bv.y), bf2f(cv.y), bf2f(dv.y));
            stash_feats(feats, c + 2, el, bf2f(xv.z), bf2f(av.z), bf2f(bv.z), bf2f(cv.z), bf2f(dv.z));
            stash_feats(feats, c + 3, el, bf2f(xv.w), bf2f(av.w), bf2f(bv.w), bf2f(cv.w), bf2f(dv.w));
        }
    }

    const int cg = t & 15;
    const int eg = t >> 4;
    float acc[2][4] = {{0.f,0.f,0.f,0.f},{0.f,0.f,0.f,0.f}};

    for (int g5 = 0; g5 < 5; ++g5) {
        __syncthreads();   // gather done / previous chunk consumed
        const float* wsrc = w + g5 * 64 * 64;
        for (int i = t * 4; i < 64 * 64; i += 256 * 4)
            *(float4*)&wlds[i] = *(const float4*)&wsrc[i];
        __syncthreads();

        const float* fbase = &feats[g5 * 64 * 36 + eg * 2];
        #pragma unroll 4
        for (int k = 0; k < 64; ++k) {
            const float2 f = *(const float2*)&fbase[k * 36];
            const float4 wv = *(const float4*)&wlds[k * 64 + cg * 4];
            acc[0][0] = fmaf(f.x, wv.x, acc[0][0]);
            acc[0][1] = fmaf(f.x, wv.y, acc[0][1]);
            acc[0][2] = fmaf(f.x, wv.z, acc[0][2]);
            acc[0][3] = fmaf(f.x, wv.w, acc[0][3]);
            acc[1][0] = fmaf(f.y, wv.x, acc[1][0]);
            acc[1][1] = fmaf(f.y, wv.y, acc[1][1]);
            acc[1][2] = fmaf(f.y, wv.z, acc[1][2]);
            acc[1][3] = fmaf(f.y, wv.w, acc[1][3]);
        }
    }

    const int c = cg * 4;
    const float4 bv = *(const float4*)&bias[c];
    const float4 gv = *(const float4*)&lng[c];
    const float4 bt = *(const float4*)&lnb[c];
    #pragma unroll
    for (int j = 0; j < 2; ++j) {
        float h0 = acc[j][0] + bv.x;
        float h1 = acc[j][1] + bv.y;
        float h2 = acc[j][2] + bv.z;
        float h3 = acc[j][3] + bv.w;
        float s = h0 + h1 + h2 + h3;
        float q = h0*h0 + h1*h1 + h2*h2 + h3*h3;
        for (int m = 1; m < 16; m <<= 1) {
            s += __shfl_xor(s, m);
            q += __shfl_xor(q, m);
        }
        const float mu   = s * (1.f / 64.f);
        const float var  = q * (1.f / 64.f) - mu * mu;
        const float rinv = rsqrtf(var + LN_EPS);
        const size_t e   = (size_t)e0 + eg * 2 + j;
        const ushort4 xpu = *(const ushort4*)&xin[e * H_DIM + c];  // residual
        ushort4 o;
        o.x = f2bf(fmaxf(fmaf((h0 - mu) * rinv, gv.x, bt.x), 0.f) + bf2f(xpu.x));
        o.y = f2bf(fmaxf(fmaf((h1 - mu) * rinv, gv.y, bt.y), 0.f) + bf2f(xpu.y));
        o.z = f2bf(fmaxf(fmaf((h2 - mu) * rinv, gv.z, bt.z), 0.f) + bf2f(xpu.z));
        o.w = f2bf(fmaxf(fmaf((h3 - mu) * rinv, gv.w, bt.w), 0.f) + bf2f(xpu.w));
        *(ushort4*)&xout[e * H_DIM + c] = o;
    }
}

// ---------------------------------------------------------------------------
// Head: relu(x @ cw1 + cb1) @ cw2 + cb2 -> logits (E,) fp32
// 32 lanes per edge; 8 edges per 256-thread block.
// ---------------------------------------------------------------------------
__global__ __launch_bounds__(256) void head_kernel(
    const u16* __restrict__ xin,
    const float* __restrict__ cw1, const float* __restrict__ cb1,
    const float* __restrict__ cw2, const float* __restrict__ cb2,
    float* __restrict__ out)
{
    __shared__ float w1[64 * 32];   // 8 KB
    __shared__ float w2[32];
    __shared__ float b1s[32];
    const int t = threadIdx.x;
    for (int i = t; i < 64 * 32; i += 256) w1[i] = cw1[i];
    if (t < 32) { w2[t] = cw2[t]; b1s[t] = cb1[t]; }
    __syncthreads();

    const int lane = t & 63;
    const int wv   = t >> 6;       // wave 0..3
    const int sub  = lane >> 5;    // which of 2 edges in this wave
    const int c    = lane & 31;    // hidden unit
    const size_t e = (size_t)blockIdx.x * 8 + wv * 2 + sub;

    const ushort4* xr4 = (const ushort4*)(xin + e * H_DIM);
    ushort4 f[16];
    #pragma unroll
    for (int i = 0; i < 16; ++i) f[i] = xr4[i];

    float z = b1s[c];
    #pragma unroll
    for (int i = 0; i < 16; ++i) {
        z = fmaf(bf2f(f[i].x), w1[(4*i+0)*32 + c], z);
        z = fmaf(bf2f(f[i].y), w1[(4*i+1)*32 + c], z);
        z = fmaf(bf2f(f[i].z), w1[(4*i+2)*32 + c], z);
        z = fmaf(bf2f(f[i].w), w1[(4*i+3)*32 + c], z);
    }
    z = fmaxf(z, 0.f);
    float r = z * w2[c];
    for (int m = 1; m < 32; m <<= 1) r += __shfl_xor(r, m);
    if (c == 0) out[e] = r + cb2[0];
}

// ---------------------------------------------------------------------------
extern "C" void kernel_launch(void* const* d_in, const int* in_sizes, int n_in,
                              void* d_out, int out_size, void* d_ws, size_t ws_size,
                              hipStream_t stream)
{
    (void)in_sizes; (void)n_in; (void)out_size; (void)ws_size;
    const float* x   = (const float*)d_in[0];
    const int*   nbr = (const int*)d_in[1];
    const float* w0  = (const float*)d_in[2];
    const float* b0  = (const float*)d_in[3];
    const float* wr  = (const float*)d_in[4];
    const float* br  = (const float*)d_in[5];
    const float* lg  = (const float*)d_in[6];
    const float* lb  = (const float*)d_in[7];
    const float* cw1 = (const float*)d_in[8];
    const float* cb1 = (const float*)d_in[9];
    const float* cw2 = (const float*)d_in[10];
    const float* cb2 = (const float*)d_in[11];
    float* out = (float*)d_out;

    u16* xa = (u16*)d_ws;                       // E x 64 bf16 (128 MB)
    u16* xb = xa + (size_t)E_EDGES * H_DIM;     // E x 64 bf16 (128 MB)

    const dim3 blk(256);
    const dim3 grid(E_EDGES / MT);              // 31250 blocks

    layer0_kernel<<<grid, blk, 0, stream>>>(x, nbr, w0, b0, lg, lb, xa);
    layer_kernel<<<grid, blk, 0, stream>>>(xa, nbr, wr,            br,       lg + 64,  lb + 64,  xb);
    layer_kernel<<<grid, blk, 0, stream>>>(xb, nbr, wr + 320*64,   br + 64,  lg + 128, lb + 128, xa);
    layer_kernel<<<grid, blk, 0, stream>>>(xa, nbr, wr + 2*320*64, br + 128, lg + 192, lb + 192, xb);
    head_kernel<<<dim3(E_EDGES / 8), blk, 0, stream>>>(xb, cw1, cb1, cw2, cb2, out);
}

// Round 3
// 1082.624 us; speedup vs baseline: 2.9769x; 2.9769x over previous
//
#include <hip/hip_runtime.h>
#include <hip/hip_bf16.h>
#include <math.h>

#define E_EDGES 1000000
#define CIN     11
#define H_DIM   64
#define LN_EPS  1e-5f

typedef unsigned short u16;
typedef __bf16 bf16x8 __attribute__((ext_vector_type(8)));
typedef float  f32x16 __attribute__((ext_vector_type(16)));

__device__ __forceinline__ float bf2f(u16 u) {
    union { unsigned int i; float f; } v; v.i = ((unsigned int)u) << 16; return v.f;
}
__device__ __forceinline__ u16 f2bf(float f) {
    union { float f; unsigned int i; } v; v.f = f;
    unsigned int x = v.i;
    return (u16)((x + 0x7FFFu + ((x >> 16) & 1u)) >> 16);   // RNE
}
// bf16x2 packed in a dword -> floats
__device__ __forceinline__ float lo2f(unsigned d) {
    union { unsigned u; float f; } v; v.u = d << 16; return v.f;
}
__device__ __forceinline__ float hi2f(unsigned d) {
    union { unsigned u; float f; } v; v.u = d & 0xffff0000u; return v.f;
}
// pack 2 floats -> bf16x2 dword (RNE, ideally v_cvt_pk_bf16_f32)
__device__ __forceinline__ unsigned pk2(float lo, float hi) {
    __hip_bfloat162 h = __float22bfloat162_rn(make_float2(lo, hi));
    unsigned r; __builtin_memcpy(&r, &h, 4); return r;
}

// ---------------------------------------------------------------------------
// Layers 1..3 (MFMA): feats(E x 320) @ W(320x64) + b -> LN -> ReLU -> +res
// Tile: 64 edges/block, 256 thr = 4 waves = (mtile 0..1) x (ntile 0..1).
// afrag/bfrag hold MFMA fragments directly: [tile][kstep][lane][8] bf16.
// 32x32x16 mfma: A lane l holds A[m=l&31][k=(l>>5)*8+j]; B same with n=l&31.
// C/D: col=l&31, row=(r&3)+8*(r>>2)+4*(l>>5)  [measured m74/m101].
// ---------------------------------------------------------------------------
__global__ __launch_bounds__(256) void layer_mfma(
    const u16* __restrict__ xin, const int* __restrict__ nbr,
    const float* __restrict__ w, const float* __restrict__ bias,
    const float* __restrict__ lng, const float* __restrict__ lnb,
    u16* __restrict__ xout)
{
    __shared__ u16 afrag[2 * 20 * 64 * 8];   // 40 KB
    __shared__ u16 bfrag[2 * 20 * 64 * 8];   // 40 KB  (80 KB total -> 2 blk/CU)

    const int t  = threadIdx.x;
    const int l  = t & 63;
    const int wv = t >> 6;
    const int e0 = blockIdx.x * 64;

    // ---- stage B fragments: W global [320][64] f32 -> bf16 frag order ----
    {
        const int lo5 = l & 31, hi8 = (l >> 5) * 8;
        #pragma unroll
        for (int i = 0; i < 10; ++i) {
            const int f  = wv * 10 + i;              // 0..39 = nt*20+ks
            const int nt = f / 20, ks = f % 20;
            const float* wp = w + (size_t)(ks * 16 + hi8) * 64 + nt * 32 + lo5;
            uint4 pk;
            pk.x = pk2(wp[0 * 64], wp[1 * 64]);
            pk.y = pk2(wp[2 * 64], wp[3 * 64]);
            pk.z = pk2(wp[4 * 64], wp[5 * 64]);
            pk.w = pk2(wp[6 * 64], wp[7 * 64]);
            *(uint4*)&bfrag[(f * 64 + l) * 8] = pk;
        }
    }

    // ---- gather + feature build -> afrag (k = g*64 + ch, kstep = g*4+cq) ----
    {
        const int el = t >> 2;                  // 0..63 local edge
        const int cq = t & 3;                   // 16-ch quarter
        const size_t e = (size_t)(e0 + el);
        const int4 n = *(const int4*)(nbr + 4 * e);
        const u16* xr = xin + e * 64            + cq * 16;
        const u16* ar = xin + (size_t)n.x * 64  + cq * 16;
        const u16* br = xin + (size_t)n.y * 64  + cq * 16;
        const u16* cr = xin + (size_t)n.z * 64  + cq * 16;
        const u16* dr = xin + (size_t)n.w * 64  + cq * 16;
        const int mt  = el >> 5;
        const int lf0 = el & 31;
        #pragma unroll
        for (int w8 = 0; w8 < 2; ++w8) {        // two 8-ch windows (= quad)
            const uint4 xv = *(const uint4*)(xr + w8 * 8);
            const uint4 av = *(const uint4*)(ar + w8 * 8);
            const uint4 bv = *(const uint4*)(br + w8 * 8);
            const uint4 cv = *(const uint4*)(cr + w8 * 8);
            const uint4 dv = *(const uint4*)(dr + w8 * 8);
            u16* base = afrag + (((mt * 20 + cq) * 64) + lf0 + w8 * 32) * 8;
            *(uint4*)base = xv;                 // group 0: x (already bf16)
            uint4 g1, g2, g3, g4;
            const unsigned* ap = (const unsigned*)&av;
            const unsigned* bp = (const unsigned*)&bv;
            const unsigned* cp = (const unsigned*)&cv;
            const unsigned* dp = (const unsigned*)&dv;
            unsigned* g1p = (unsigned*)&g1; unsigned* g2p = (unsigned*)&g2;
            unsigned* g3p = (unsigned*)&g3; unsigned* g4p = (unsigned*)&g4;
            #pragma unroll
            for (int i = 0; i < 4; ++i) {
                const float a0 = lo2f(ap[i]), a1 = hi2f(ap[i]);
                const float c0 = lo2f(cp[i]), c1 = hi2f(cp[i]);
                g1p[i] = pk2(fabsf(a0 - c0), fabsf(a1 - c1));
                g2p[i] = pk2(a0 + c0, a1 + c1);
                const float b0 = lo2f(bp[i]), b1 = hi2f(bp[i]);
                const float d0 = lo2f(dp[i]), d1 = hi2f(dp[i]);
                g3p[i] = pk2(fabsf(b0 - d0), fabsf(b1 - d1));
                g4p[i] = pk2(b0 + d0, b1 + d1);
            }
            *(uint4*)(base + 1 * 2048) = g1;    // group stride = 4 ksteps = 2048 u16
            *(uint4*)(base + 2 * 2048) = g2;
            *(uint4*)(base + 3 * 2048) = g3;
            *(uint4*)(base + 4 * 2048) = g4;
        }
    }
    __syncthreads();

    // ---- MFMA GEMM: wave (mt, nt) computes 32 edges x 32 ch over K=320 ----
    const int mt = wv >> 1, nt = wv & 1;
    f32x16 acc = {};
    const u16* ab = afrag + mt * (20 * 512) + l * 8;
    const u16* bb = bfrag + nt * (20 * 512) + l * 8;
    #pragma unroll
    for (int ks = 0; ks < 20; ++ks) {
        const bf16x8 a8 = *(const bf16x8*)(ab + ks * 512);
        const bf16x8 b8 = *(const bf16x8*)(bb + ks * 512);
        acc = __builtin_amdgcn_mfma_f32_32x32x16_bf16(a8, b8, acc, 0, 0, 0);
    }
    __syncthreads();   // afrag reads done; reuse as epilogue buffer

    // ---- epilogue: C + bias -> LDS [64][68] f32 ----
    float* ebuf = (float*)afrag;               // 64*68*4 = 17.4 KB < 40 KB
    {
        const int col  = nt * 32 + (l & 31);
        const float bc = bias[col];
        const int quad = l >> 5;
        #pragma unroll
        for (int r = 0; r < 16; ++r) {
            const int row = mt * 32 + (r & 3) + 8 * (r >> 2) + 4 * quad;
            ebuf[row * 68 + col] = acc[r] + bc;
        }
    }
    __syncthreads();

    // ---- LN + ReLU + residual -> bf16 store ----
    {
        const int el = t >> 2, q = t & 3;
        const float* rp = ebuf + el * 68 + q * 16;
        float v[16];
        float s = 0.f, qs = 0.f;
        #pragma unroll
        for (int i = 0; i < 16; ++i) { v[i] = rp[i]; s += v[i]; qs += v[i] * v[i]; }
        s  += __shfl_xor(s, 1);  s  += __shfl_xor(s, 2);
        qs += __shfl_xor(qs, 1); qs += __shfl_xor(qs, 2);
        const float mu   = s * (1.f / 64.f);
        const float var  = qs * (1.f / 64.f) - mu * mu;
        const float rinv = rsqrtf(var + LN_EPS);
        const size_t e   = (size_t)(e0 + el);
        const u16* resp  = xin + e * 64 + q * 16;
        u16* outp        = xout + e * 64 + q * 16;
        #pragma unroll
        for (int h = 0; h < 2; ++h) {
            const uint4 res = *(const uint4*)(resp + h * 8);
            const unsigned* rr = (const unsigned*)&res;
            uint4 o; unsigned* op = (unsigned*)&o;
            #pragma unroll
            for (int i = 0; i < 4; ++i) {
                const int ci = q * 16 + h * 8 + i * 2;
                const float y0 = fmaxf(fmaf((v[h*8 + i*2]     - mu) * rinv, lng[ci],     lnb[ci]),     0.f) + lo2f(rr[i]);
                const float y1 = fmaxf(fmaf((v[h*8 + i*2 + 1] - mu) * rinv, lng[ci + 1], lnb[ci + 1]), 0.f) + hi2f(rr[i]);
                op[i] = pk2(y0, y1);
            }
            *(uint4*)(outp + h * 8) = o;
        }
    }
}

// ---------------------------------------------------------------------------
// Layer 0 (unchanged fp32 path): feats(E x 55) @ w0(55x64) -> LN -> ReLU
// ---------------------------------------------------------------------------
__global__ __launch_bounds__(256) void layer0_kernel(
    const float* __restrict__ x, const int* __restrict__ nbr,
    const float* __restrict__ w0, const float* __restrict__ b0,
    const float* __restrict__ lng, const float* __restrict__ lnb,
    u16* __restrict__ xout)
{
    __shared__ float feats[55 * 36];
    __shared__ float wlds[55 * 64];
    const int t  = threadIdx.x;
    const int e0 = blockIdx.x * 32;

    for (int i = t; i < 55 * 64; i += 256) wlds[i] = w0[i];

    {
        const int tid8 = t & 7;
        const int el   = t >> 3;
        const int e    = e0 + el;
        const int4 n   = *(const int4*)(nbr + 4ull * (unsigned)e);
        for (int c = tid8; c < CIN; c += 8) {
            const float xv = x[(size_t)e   * CIN + c];
            const float av = x[(size_t)n.x * CIN + c];
            const float bv = x[(size_t)n.y * CIN + c];
            const float cv = x[(size_t)n.z * CIN + c];
            const float dv = x[(size_t)n.w * CIN + c];
            feats[(0*CIN + c) * 36 + el] = xv;
            feats[(1*CIN + c) * 36 + el] = fabsf(av - cv);
            feats[(2*CIN + c) * 36 + el] = av + cv;
            feats[(3*CIN + c) * 36 + el] = fabsf(bv - dv);
            feats[(4*CIN + c) * 36 + el] = bv + dv;
        }
    }
    __syncthreads();

    const int cg = t & 15;
    const int eg = t >> 4;
    float acc[2][4] = {{0.f,0.f,0.f,0.f},{0.f,0.f,0.f,0.f}};
    #pragma unroll 5
    for (int k = 0; k < 55; ++k) {
        const float2 f = *(const float2*)&feats[k * 36 + eg * 2];
        const float4 w = *(const float4*)&wlds[k * 64 + cg * 4];
        acc[0][0] = fmaf(f.x, w.x, acc[0][0]);
        acc[0][1] = fmaf(f.x, w.y, acc[0][1]);
        acc[0][2] = fmaf(f.x, w.z, acc[0][2]);
        acc[0][3] = fmaf(f.x, w.w, acc[0][3]);
        acc[1][0] = fmaf(f.y, w.x, acc[1][0]);
        acc[1][1] = fmaf(f.y, w.y, acc[1][1]);
        acc[1][2] = fmaf(f.y, w.z, acc[1][2]);
        acc[1][3] = fmaf(f.y, w.w, acc[1][3]);
    }

    const int c = cg * 4;
    const float4 bv = *(const float4*)&b0[c];
    const float4 gv = *(const float4*)&lng[c];
    const float4 bt = *(const float4*)&lnb[c];
    #pragma unroll
    for (int j = 0; j < 2; ++j) {
        float h0 = acc[j][0] + bv.x;
        float h1 = acc[j][1] + bv.y;
        float h2 = acc[j][2] + bv.z;
        float h3 = acc[j][3] + bv.w;
        float s = h0 + h1 + h2 + h3;
        float q = h0*h0 + h1*h1 + h2*h2 + h3*h3;
        for (int m = 1; m < 16; m <<= 1) {
            s += __shfl_xor(s, m);
            q += __shfl_xor(q, m);
        }
        const float mu   = s * (1.f / 64.f);
        const float var  = q * (1.f / 64.f) - mu * mu;
        const float rinv = rsqrtf(var + LN_EPS);
        const size_t e   = (size_t)e0 + eg * 2 + j;
        ushort4 o;
        o.x = f2bf(fmaxf(fmaf((h0 - mu) * rinv, gv.x, bt.x), 0.f));
        o.y = f2bf(fmaxf(fmaf((h1 - mu) * rinv, gv.y, bt.y), 0.f));
        o.z = f2bf(fmaxf(fmaf((h2 - mu) * rinv, gv.z, bt.z), 0.f));
        o.w = f2bf(fmaxf(fmaf((h3 - mu) * rinv, gv.w, bt.w), 0.f));
        *(ushort4*)&xout[e * H_DIM + c] = o;
    }
}

// ---------------------------------------------------------------------------
// Head (unchanged): relu(x @ cw1 + cb1) @ cw2 + cb2 -> logits (E,) fp32
// ---------------------------------------------------------------------------
__global__ __launch_bounds__(256) void head_kernel(
    const u16* __restrict__ xin,
    const float* __restrict__ cw1, const float* __restrict__ cb1,
    const float* __restrict__ cw2, const float* __restrict__ cb2,
    float* __restrict__ out)
{
    __shared__ float w1[64 * 32];
    __shared__ float w2[32];
    __shared__ float b1s[32];
    const int t = threadIdx.x;
    for (int i = t; i < 64 * 32; i += 256) w1[i] = cw1[i];
    if (t < 32) { w2[t] = cw2[t]; b1s[t] = cb1[t]; }
    __syncthreads();

    const int lane = t & 63;
    const int wv   = t >> 6;
    const int sub  = lane >> 5;
    const int c    = lane & 31;
    const size_t e = (size_t)blockIdx.x * 8 + wv * 2 + sub;

    const ushort4* xr4 = (const ushort4*)(xin + e * H_DIM);
    ushort4 f[16];
    #pragma unroll
    for (int i = 0; i < 16; ++i) f[i] = xr4[i];

    float z = b1s[c];
    #pragma unroll
    for (int i = 0; i < 16; ++i) {
        z = fmaf(bf2f(f[i].x), w1[(4*i+0)*32 + c], z);
        z = fmaf(bf2f(f[i].y), w1[(4*i+1)*32 + c], z);
        z = fmaf(bf2f(f[i].z), w1[(4*i+2)*32 + c], z);
        z = fmaf(bf2f(f[i].w), w1[(4*i+3)*32 + c], z);
    }
    z = fmaxf(z, 0.f);
    float r = z * w2[c];
    for (int m = 1; m < 32; m <<= 1) r += __shfl_xor(r, m);
    if (c == 0) out[e] = r + cb2[0];
}

// ---------------------------------------------------------------------------
extern "C" void kernel_launch(void* const* d_in, const int* in_sizes, int n_in,
                              void* d_out, int out_size, void* d_ws, size_t ws_size,
                              hipStream_t stream)
{
    (void)in_sizes; (void)n_in; (void)out_size; (void)ws_size;
    const float* x   = (const float*)d_in[0];
    const int*   nbr = (const int*)d_in[1];
    const float* w0  = (const float*)d_in[2];
    const float* b0  = (const float*)d_in[3];
    const float* wr  = (const float*)d_in[4];
    const float* br  = (const float*)d_in[5];
    const float* lg  = (const float*)d_in[6];
    const float* lb  = (const float*)d_in[7];
    const float* cw1 = (const float*)d_in[8];
    const float* cb1 = (const float*)d_in[9];
    const float* cw2 = (const float*)d_in[10];
    const float* cb2 = (const float*)d_in[11];
    float* out = (float*)d_out;

    u16* xa = (u16*)d_ws;                       // E x 64 bf16 (128 MB)
    u16* xb = xa + (size_t)E_EDGES * H_DIM;     // E x 64 bf16 (128 MB)

    layer0_kernel<<<dim3(E_EDGES / 32), dim3(256), 0, stream>>>(x, nbr, w0, b0, lg, lb, xa);
    layer_mfma<<<dim3(E_EDGES / 64), dim3(256), 0, stream>>>(xa, nbr, wr,              br,       lg + 64,  lb + 64,  xb);
    layer_mfma<<<dim3(E_EDGES / 64), dim3(256), 0, stream>>>(xb, nbr, wr + 320*64,     br + 64,  lg + 128, lb + 128, xa);
    layer_mfma<<<dim3(E_EDGES / 64), dim3(256), 0, stream>>>(xa, nbr, wr + 2*320*64,   br + 128, lg + 192, lb + 192, xb);
    head_kernel<<<dim3(E_EDGES / 8), dim3(256), 0, stream>>>(xb, cw1, cb1, cw2, cb2, out);
}

// Round 4
// 922.511 us; speedup vs baseline: 3.4936x; 1.1736x over previous
//
#include <hip/hip_runtime.h>
#include <hip/hip_bf16.h>
#include <math.h>

#define E_EDGES 1000000
#define LN_EPS  1e-5f

typedef unsigned short u16;
typedef __bf16 bf16x8 __attribute__((ext_vector_type(8)));
typedef float  f32x16 __attribute__((ext_vector_type(16)));

__device__ __forceinline__ float lo2f(unsigned d) {
    union { unsigned u; float f; } v; v.u = d << 16; return v.f;
}
__device__ __forceinline__ float hi2f(unsigned d) {
    union { unsigned u; float f; } v; v.u = d & 0xffff0000u; return v.f;
}
__device__ __forceinline__ unsigned pk2(float lo, float hi) {
    __hip_bfloat162 h = __float22bfloat162_rn(make_float2(lo, hi));
    unsigned r; __builtin_memcpy(&r, &h, 4); return r;
}

// ---------------------------------------------------------------------------
// Weight -> bf16 MFMA B-fragment conversion (one-time per launch, ~128 KB).
// Frag layout per layer: slot s = (ks*2+nt)*64 + l, 8 bf16 per slot:
//   B[k = ks*16 + (l>>5)*8 + j][n = nt*32 + (l&31)]
// Layers 1..3: ks 0..19 (2560 slots each). Layer0: ks 0..3, K padded 55->64.
// Stored in d_out scratch (head_mfma overwrites d_out afterwards).
// ---------------------------------------------------------------------------
__global__ __launch_bounds__(256) void wconv_kernel(
    const float* __restrict__ wr, const float* __restrict__ w0,
    u16* __restrict__ wf)
{
    const int s = blockIdx.x * 256 + threadIdx.x;   // 0..8191
    const int l    = s & 63;
    const int nt   = (s >> 6) & 1;                  // 2560 and 7680 are multiples of 128
    const int col  = nt * 32 + (l & 31);
    const int half = l >> 5;
    uint4 pk;
    if (s < 3 * 2560) {
        const int L  = s / 2560;
        const int sl = s % 2560;
        const int kb = (sl >> 7) * 16 + half * 8;
        const float* W = wr + L * 320 * 64;
        pk.x = pk2(W[(kb+0)*64+col], W[(kb+1)*64+col]);
        pk.y = pk2(W[(kb+2)*64+col], W[(kb+3)*64+col]);
        pk.z = pk2(W[(kb+4)*64+col], W[(kb+5)*64+col]);
        pk.w = pk2(W[(kb+6)*64+col], W[(kb+7)*64+col]);
    } else {
        const int sl = s - 3 * 2560;
        const int kb = (sl >> 7) * 16 + half * 8;
        float v[8];
        #pragma unroll
        for (int p = 0; p < 8; ++p) v[p] = (kb + p < 55) ? w0[(kb+p)*64 + col] : 0.f;
        pk.x = pk2(v[0],v[1]); pk.y = pk2(v[2],v[3]);
        pk.z = pk2(v[4],v[5]); pk.w = pk2(v[6],v[7]);
    }
    *(uint4*)&wf[(size_t)s * 8] = pk;
}

// ---------------------------------------------------------------------------
// Layers 1..3: feats(E x 320) @ W + b -> LN -> ReLU -> +residual.
// 128 edges/block, 4 waves; wave wv = mtile (32 edges) x full N=64.
// A-frags in LDS (80 KB); B-frags straight from global (L1/L2-hot).
// ---------------------------------------------------------------------------
__global__ __launch_bounds__(256) void layer_mfma(
    const u16* __restrict__ xin, const int* __restrict__ nbr,
    const u16* __restrict__ wf, const float* __restrict__ bias,
    const float* __restrict__ lng, const float* __restrict__ lnb,
    u16* __restrict__ xout)
{
    __shared__ u16 afrag[4 * 20 * 64 * 8];   // 80 KB -> 2 blocks/CU
    const int t  = threadIdx.x;
    const int l  = t & 63;
    const int wv = t >> 6;
    const int e0 = blockIdx.x * 128;

    // ---- gather + feature build: 2 threads/edge (cq = 32-ch half) ----
    {
        const int el = t >> 1;
        const int cq = t & 1;
        const size_t e  = (size_t)(e0 + el);
        const size_t ec = e < E_EDGES ? e : (size_t)(E_EDGES - 1);
        const int4 n = *(const int4*)(nbr + 4 * ec);
        const u16* xr = xin + ec * 64            + cq * 32;
        const u16* ar = xin + (size_t)n.x * 64   + cq * 32;
        const u16* br = xin + (size_t)n.y * 64   + cq * 32;
        const u16* cr = xin + (size_t)n.z * 64   + cq * 32;
        const u16* dr = xin + (size_t)n.w * 64   + cq * 32;
        const int mt    = el >> 5;
        const int lane0 = el & 31;
        u16* abase = afrag + (size_t)mt * (20 * 64 * 8);
        #pragma unroll
        for (int w8 = 0; w8 < 4; ++w8) {          // 8-ch windows
            const uint4 xv = *(const uint4*)(xr + w8 * 8);
            const uint4 av = *(const uint4*)(ar + w8 * 8);
            const uint4 bv = *(const uint4*)(br + w8 * 8);
            const uint4 cv = *(const uint4*)(cr + w8 * 8);
            const uint4 dv = *(const uint4*)(dr + w8 * 8);
            const int ch0  = cq * 32 + w8 * 8;
            const int half = (ch0 >> 3) & 1;
            const int kq   = ch0 >> 4;            // k-sixteenth within the 64-ch group
            const int ldst = lane0 + 32 * half;
            uint4 g1, g2, g3, g4;
            const unsigned* ap = (const unsigned*)&av;
            const unsigned* bp = (const unsigned*)&bv;
            const unsigned* cp = (const unsigned*)&cv;
            const unsigned* dp = (const unsigned*)&dv;
            unsigned* g1p = (unsigned*)&g1; unsigned* g2p = (unsigned*)&g2;
            unsigned* g3p = (unsigned*)&g3; unsigned* g4p = (unsigned*)&g4;
            #pragma unroll
            for (int i = 0; i < 4; ++i) {
                const float a0 = lo2f(ap[i]), a1 = hi2f(ap[i]);
                const float c0 = lo2f(cp[i]), c1 = hi2f(cp[i]);
                g1p[i] = pk2(fabsf(a0 - c0), fabsf(a1 - c1));
                g2p[i] = pk2(a0 + c0, a1 + c1);
                const float b0 = lo2f(bp[i]), b1 = hi2f(bp[i]);
                const float d0 = lo2f(dp[i]), d1 = hi2f(dp[i]);
                g3p[i] = pk2(fabsf(b0 - d0), fabsf(b1 - d1));
                g4p[i] = pk2(b0 + d0, b1 + d1);
            }
            // group g -> kstep = g*4 + kq
            *(uint4*)(abase + (size_t)(((0*4 + kq) * 64) + ldst) * 8) = xv;
            *(uint4*)(abase + (size_t)(((1*4 + kq) * 64) + ldst) * 8) = g1;
            *(uint4*)(abase + (size_t)(((2*4 + kq) * 64) + ldst) * 8) = g2;
            *(uint4*)(abase + (size_t)(((3*4 + kq) * 64) + ldst) * 8) = g3;
            *(uint4*)(abase + (size_t)(((4*4 + kq) * 64) + ldst) * 8) = g4;
        }
    }
    __syncthreads();

    // ---- K-loop: 20 ksteps, A from LDS, B0/B1 from global frags ----
    f32x16 acc0 = {}, acc1 = {};
    const u16* ab = afrag + (size_t)wv * (20 * 64 * 8) + l * 8;
    #pragma unroll
    for (int ks = 0; ks < 20; ++ks) {
        const bf16x8 a8 = *(const bf16x8*)(ab + ks * 512);
        const bf16x8 b0 = *(const bf16x8*)(wf + (size_t)((ks*2    ) * 64 + l) * 8);
        const bf16x8 b1 = *(const bf16x8*)(wf + (size_t)((ks*2 + 1) * 64 + l) * 8);
        acc0 = __builtin_amdgcn_mfma_f32_32x32x16_bf16(a8, b0, acc0, 0, 0, 0);
        acc1 = __builtin_amdgcn_mfma_f32_32x32x16_bf16(a8, b1, acc1, 0, 0, 0);
    }
    __syncthreads();

    // ---- epilogue: C + bias -> ebuf [128][68] ----
    float* ebuf = (float*)afrag;
    {
        const int col0 = l & 31;
        const int quad = l >> 5;
        const float bc0 = bias[col0];
        const float bc1 = bias[col0 + 32];
        #pragma unroll
        for (int r = 0; r < 16; ++r) {
            const int row = wv * 32 + (r & 3) + 8 * (r >> 2) + 4 * quad;
            ebuf[row * 68 + col0]      = acc0[r] + bc0;
            ebuf[row * 68 + col0 + 32] = acc1[r] + bc1;
        }
    }
    __syncthreads();

    // ---- LN + ReLU + residual -> bf16 store (2 threads/edge) ----
    {
        const int el = t >> 1, hf = t & 1;
        const float* rp = ebuf + el * 68 + hf * 32;
        float v[32];
        float s = 0.f, q = 0.f;
        #pragma unroll
        for (int i = 0; i < 32; ++i) { v[i] = rp[i]; s += v[i]; q += v[i] * v[i]; }
        s += __shfl_xor(s, 1); q += __shfl_xor(q, 1);
        const float mu   = s * (1.f / 64.f);
        const float var  = q * (1.f / 64.f) - mu * mu;
        const float rinv = rsqrtf(var + LN_EPS);
        const size_t e = (size_t)(e0 + el);
        if (e < E_EDGES) {
            const u16* resp = xin + e * 64 + hf * 32;
            u16* outp       = xout + e * 64 + hf * 32;
            const float* gp = lng + hf * 32;
            const float* bp = lnb + hf * 32;
            #pragma unroll
            for (int w8 = 0; w8 < 4; ++w8) {
                const uint4 res = *(const uint4*)(resp + w8 * 8);
                const unsigned* rr = (const unsigned*)&res;
                uint4 o; unsigned* op = (unsigned*)&o;
                #pragma unroll
                for (int i = 0; i < 4; ++i) {
                    const int ci = w8 * 8 + i * 2;
                    const float y0 = fmaxf(fmaf((v[ci]   - mu) * rinv, gp[ci],   bp[ci]),   0.f) + lo2f(rr[i]);
                    const float y1 = fmaxf(fmaf((v[ci+1] - mu) * rinv, gp[ci+1], bp[ci+1]), 0.f) + hi2f(rr[i]);
                    op[i] = pk2(y0, y1);
                }
                *(uint4*)(outp + w8 * 8) = o;
            }
        }
    }
}

// ---------------------------------------------------------------------------
// Layer 0 (MFMA, K padded 55->64): feats(E x 55) @ w0 -> LN -> ReLU.
// x is fp32 E x 11. 2 threads/edge: h = t>>7 builds k-range [h*32, h*32+32).
// ---------------------------------------------------------------------------
__global__ __launch_bounds__(256) void layer0_mfma(
    const float* __restrict__ x, const int* __restrict__ nbr,
    const u16* __restrict__ wf0, const float* __restrict__ bias,
    const float* __restrict__ lng, const float* __restrict__ lnb,
    u16* __restrict__ xout)
{
    __shared__ float smem[128 * 68];          // 34.8 KB (afrag aliased: 16 KB)
    u16* afrag = (u16*)smem;
    const int t  = threadIdx.x;
    const int l  = t & 63;
    const int wv = t >> 6;
    const int e0 = blockIdx.x * 128;

    {
        const int el = t & 127;
        const int h  = t >> 7;                // wave-uniform
        const size_t e  = (size_t)(e0 + el);
        const size_t ec = e < E_EDGES ? e : (size_t)(E_EDGES - 1);
        const int4 n = *(const int4*)(nbr + 4 * ec);
        const float* xr = x + ec * 11;
        const float* ar = x + (size_t)n.x * 11;
        const float* br = x + (size_t)n.y * 11;
        const float* cr = x + (size_t)n.z * 11;
        const float* dr = x + (size_t)n.w * 11;
        float f[32];
        if (h == 0) {
            #pragma unroll
            for (int i = 0; i < 11; ++i) f[i] = xr[i];
            #pragma unroll
            for (int i = 0; i < 11; ++i) { const float a = ar[i], c = cr[i];
                f[11 + i] = fabsf(a - c); if (i < 10) f[22 + i] = a + c; }
        } else {
            f[0] = ar[10] + cr[10];                       // k = 32
            #pragma unroll
            for (int i = 0; i < 11; ++i) { const float b = br[i], d = dr[i];
                f[1 + i] = fabsf(b - d); f[12 + i] = b + d; }
            #pragma unroll
            for (int i = 23; i < 32; ++i) f[i] = 0.f;     // k 55..63 pad
        }
        const int mt    = el >> 5;
        const int lane0 = el & 31;
        u16* abase = afrag + (size_t)mt * (4 * 64 * 8);
        #pragma unroll
        for (int s8 = 0; s8 < 4; ++s8) {
            const int k0   = h * 32 + s8 * 8;
            const int ks   = k0 >> 4;
            const int half = (k0 >> 3) & 1;
            uint4 pk;
            pk.x = pk2(f[s8*8+0], f[s8*8+1]);
            pk.y = pk2(f[s8*8+2], f[s8*8+3]);
            pk.z = pk2(f[s8*8+4], f[s8*8+5]);
            pk.w = pk2(f[s8*8+6], f[s8*8+7]);
            *(uint4*)(abase + (size_t)(ks * 64 + lane0 + 32 * half) * 8) = pk;
        }
    }
    __syncthreads();

    f32x16 acc0 = {}, acc1 = {};
    const u16* ab = afrag + (size_t)wv * (4 * 64 * 8) + l * 8;
    #pragma unroll
    for (int ks = 0; ks < 4; ++ks) {
        const bf16x8 a8 = *(const bf16x8*)(ab + ks * 512);
        const bf16x8 b0 = *(const bf16x8*)(wf0 + (size_t)((ks*2    ) * 64 + l) * 8);
        const bf16x8 b1 = *(const bf16x8*)(wf0 + (size_t)((ks*2 + 1) * 64 + l) * 8);
        acc0 = __builtin_amdgcn_mfma_f32_32x32x16_bf16(a8, b0, acc0, 0, 0, 0);
        acc1 = __builtin_amdgcn_mfma_f32_32x32x16_bf16(a8, b1, acc1, 0, 0, 0);
    }
    __syncthreads();

    float* ebuf = smem;
    {
        const int col0 = l & 31;
        const int quad = l >> 5;
        const float bc0 = bias[col0];
        const float bc1 = bias[col0 + 32];
        #pragma unroll
        for (int r = 0; r < 16; ++r) {
            const int row = wv * 32 + (r & 3) + 8 * (r >> 2) + 4 * quad;
            ebuf[row * 68 + col0]      = acc0[r] + bc0;
            ebuf[row * 68 + col0 + 32] = acc1[r] + bc1;
        }
    }
    __syncthreads();

    {
        const int el = t >> 1, hf = t & 1;
        const float* rp = ebuf + el * 68 + hf * 32;
        float v[32];
        float s = 0.f, q = 0.f;
        #pragma unroll
        for (int i = 0; i < 32; ++i) { v[i] = rp[i]; s += v[i]; q += v[i] * v[i]; }
        s += __shfl_xor(s, 1); q += __shfl_xor(q, 1);
        const float mu   = s * (1.f / 64.f);
        const float var  = q * (1.f / 64.f) - mu * mu;
        const float rinv = rsqrtf(var + LN_EPS);
        const size_t e = (size_t)(e0 + el);
        if (e < E_EDGES) {
            u16* outp       = xout + e * 64 + hf * 32;
            const float* gp = lng + hf * 32;
            const float* bp = lnb + hf * 32;
            #pragma unroll
            for (int w8 = 0; w8 < 4; ++w8) {
                uint4 o; unsigned* op = (unsigned*)&o;
                #pragma unroll
                for (int i = 0; i < 4; ++i) {
                    const int ci = w8 * 8 + i * 2;
                    const float y0 = fmaxf(fmaf((v[ci]   - mu) * rinv, gp[ci],   bp[ci]),   0.f);
                    const float y1 = fmaxf(fmaf((v[ci+1] - mu) * rinv, gp[ci+1], bp[ci+1]), 0.f);
                    op[i] = pk2(y0, y1);
                }
                *(uint4*)(outp + w8 * 8) = o;
            }
        }
    }
}

// ---------------------------------------------------------------------------
// Head (MFMA): logits = relu(x @ cw1 + cb1) @ cw2 + cb2.
// Wave-per-32-edge tile, grid-stride; A straight from global, B in registers.
// ---------------------------------------------------------------------------
__global__ __launch_bounds__(256) void head_mfma(
    const u16* __restrict__ xin,
    const float* __restrict__ cw1, const float* __restrict__ cb1,
    const float* __restrict__ cw2, const float* __restrict__ cb2,
    float* __restrict__ out)
{
    const int t    = threadIdx.x;
    const int l    = t & 63;
    const int wv   = t >> 6;
    const int col  = l & 31;
    const int half = l >> 5;

    bf16x8 bf[4];
    #pragma unroll
    for (int ks = 0; ks < 4; ++ks) {
        const int kb = ks * 16 + half * 8;
        uint4 pk;
        pk.x = pk2(cw1[(kb+0)*32 + col], cw1[(kb+1)*32 + col]);
        pk.y = pk2(cw1[(kb+2)*32 + col], cw1[(kb+3)*32 + col]);
        pk.z = pk2(cw1[(kb+4)*32 + col], cw1[(kb+5)*32 + col]);
        pk.w = pk2(cw1[(kb+6)*32 + col], cw1[(kb+7)*32 + col]);
        __builtin_memcpy(&bf[ks], &pk, 16);
    }
    const float bc = cb1[col];
    const float w2 = cw2[col];
    const float b2 = cb2[0];

    const int nwaves = gridDim.x * 4;
    for (int tile = blockIdx.x * 4 + wv; tile < E_EDGES / 32; tile += nwaves) {
        const size_t e0 = (size_t)tile * 32;
        const u16* xb = xin + (e0 + col) * 64 + half * 8;
        f32x16 acc = {};
        #pragma unroll
        for (int ks = 0; ks < 4; ++ks) {
            const bf16x8 a8 = *(const bf16x8*)(xb + ks * 16);
            acc = __builtin_amdgcn_mfma_f32_32x32x16_bf16(a8, bf[ks], acc, 0, 0, 0);
        }
        float sums[16];
        #pragma unroll
        for (int r = 0; r < 16; ++r) {
            float z = fmaxf(acc[r] + bc, 0.f) * w2;
            z += __shfl_xor(z, 1); z += __shfl_xor(z, 2); z += __shfl_xor(z, 4);
            z += __shfl_xor(z, 8); z += __shfl_xor(z, 16);
            sums[r] = z;
        }
        if (col == 0) {
            #pragma unroll
            for (int r = 0; r < 16; ++r) {
                const int row = (r & 3) + 8 * (r >> 2) + 4 * half;
                out[e0 + row] = sums[r] + b2;
            }
        }
    }
}

// ---------------------------------------------------------------------------
extern "C" void kernel_launch(void* const* d_in, const int* in_sizes, int n_in,
                              void* d_out, int out_size, void* d_ws, size_t ws_size,
                              hipStream_t stream)
{
    (void)in_sizes; (void)n_in; (void)out_size; (void)ws_size;
    const float* x   = (const float*)d_in[0];
    const int*   nbr = (const int*)d_in[1];
    const float* w0  = (const float*)d_in[2];
    const float* b0  = (const float*)d_in[3];
    const float* wr  = (const float*)d_in[4];
    const float* br  = (const float*)d_in[5];
    const float* lg  = (const float*)d_in[6];
    const float* lb  = (const float*)d_in[7];
    const float* cw1 = (const float*)d_in[8];
    const float* cb1 = (const float*)d_in[9];
    const float* cw2 = (const float*)d_in[10];
    const float* cb2 = (const float*)d_in[11];
    float* out = (float*)d_out;

    u16* xa = (u16*)d_ws;                       // E x 64 bf16 (128 MB)
    u16* xb = xa + (size_t)E_EDGES * 64;        // E x 64 bf16 (128 MB)
    u16* wfrag = (u16*)d_out;                   // 128 KB scratch; head overwrites d_out

    const dim3 blk(256);
    const int  grid_l = (E_EDGES + 127) / 128;  // 7813

    wconv_kernel<<<dim3(32), blk, 0, stream>>>(wr, w0, wfrag);
    layer0_mfma<<<dim3(grid_l), blk, 0, stream>>>(x, nbr, wfrag + 3*20480, b0, lg, lb, xa);
    layer_mfma<<<dim3(grid_l), blk, 0, stream>>>(xa, nbr, wfrag,           br,        lg + 64,  lb + 64,  xb);
    layer_mfma<<<dim3(grid_l), blk, 0, stream>>>(xb, nbr, wfrag + 20480,   br + 64,   lg + 128, lb + 128, xa);
    layer_mfma<<<dim3(grid_l), blk, 0, stream>>>(xa, nbr, wfrag + 40960,   br + 128,  lg + 192, lb + 192, xb);
    head_mfma<<<dim3(2048), blk, 0, stream>>>(xb, cw1, cb1, cw2, cb2, out);
}

// Round 5
// 695.177 us; speedup vs baseline: 4.6360x; 1.3270x over previous
//
#include <hip/hip_runtime.h>
#include <hip/hip_bf16.h>
#include <math.h>

#define E_EDGES 1000000
#define LN_EPS  1e-5f

typedef unsigned short u16;
typedef __bf16 bf16x8 __attribute__((ext_vector_type(8)));
typedef float  f32x16 __attribute__((ext_vector_type(16)));

__device__ __forceinline__ float lo2f(unsigned d) {
    union { unsigned u; float f; } v; v.u = d << 16; return v.f;
}
__device__ __forceinline__ float hi2f(unsigned d) {
    union { unsigned u; float f; } v; v.u = d & 0xffff0000u; return v.f;
}
__device__ __forceinline__ unsigned pk2(float lo, float hi) {
    __hip_bfloat162 h = __float22bfloat162_rn(make_float2(lo, hi));
    unsigned r; __builtin_memcpy(&r, &h, 4); return r;
}

// ---------------------------------------------------------------------------
// Weight -> bf16 MFMA B-fragment conversion (one-time per launch, ~128 KB).
// Frag layout per layer: slot s = (ks*2+nt)*64 + l, 8 bf16 per slot:
//   B[k = ks*16 + (l>>5)*8 + j][n = nt*32 + (l&31)]
// Layers 1..3: ks 0..19 (2560 slots each). Layer0: ks 0..3, K padded 55->64.
// Stored in d_out scratch (head_mfma overwrites d_out afterwards).
// ---------------------------------------------------------------------------
__global__ __launch_bounds__(256) void wconv_kernel(
    const float* __restrict__ wr, const float* __restrict__ w0,
    u16* __restrict__ wf)
{
    const int s = blockIdx.x * 256 + threadIdx.x;   // 0..8191
    const int l    = s & 63;
    const int nt   = (s >> 6) & 1;                  // 2560 and 7680 are multiples of 128
    const int col  = nt * 32 + (l & 31);
    const int half = l >> 5;
    uint4 pk;
    if (s < 3 * 2560) {
        const int L  = s / 2560;
        const int sl = s % 2560;
        const int kb = (sl >> 7) * 16 + half * 8;
        const float* W = wr + L * 320 * 64;
        pk.x = pk2(W[(kb+0)*64+col], W[(kb+1)*64+col]);
        pk.y = pk2(W[(kb+2)*64+col], W[(kb+3)*64+col]);
        pk.z = pk2(W[(kb+4)*64+col], W[(kb+5)*64+col]);
        pk.w = pk2(W[(kb+6)*64+col], W[(kb+7)*64+col]);
    } else {
        const int sl = s - 3 * 2560;
        const int kb = (sl >> 7) * 16 + half * 8;
        float v[8];
        #pragma unroll
        for (int p = 0; p < 8; ++p) v[p] = (kb + p < 55) ? w0[(kb+p)*64 + col] : 0.f;
        pk.x = pk2(v[0],v[1]); pk.y = pk2(v[2],v[3]);
        pk.z = pk2(v[4],v[5]); pk.w = pk2(v[6],v[7]);
    }
    *(uint4*)&wf[(size_t)s * 8] = pk;
}

// ---------------------------------------------------------------------------
// Layers 1..3: feats(E x 320) @ W + b -> LN -> ReLU -> +residual.
// 64 edges/block, 4 waves = (mtile 0..1) x (ntile 0..1), one f32x16 acc each.
// afrag 40 KB -> 4 blocks/CU; __launch_bounds__(256,4) pins VGPR <= 128.
// B-frags read from global (L1-resident, 20 KB per ntile).
// ---------------------------------------------------------------------------
__global__ __launch_bounds__(256, 4) void layer_mfma(
    const u16* __restrict__ xin, const int* __restrict__ nbr,
    const u16* __restrict__ wf, const float* __restrict__ bias,
    const float* __restrict__ lng, const float* __restrict__ lnb,
    u16* __restrict__ xout)
{
    __shared__ u16 afrag[2 * 20 * 64 * 8];   // 40 KB
    const int t  = threadIdx.x;
    const int l  = t & 63;
    const int wv = t >> 6;
    const int e0 = blockIdx.x * 64;          // grid exact: 15625*64 = 1e6

    // ---- gather + feature build: 4 threads/edge (cq = 16-ch quarter) ----
    {
        const int el = t >> 2;               // 0..63
        const int cq = t & 3;
        const size_t e = (size_t)(e0 + el);
        const int4 n = *(const int4*)(nbr + 4 * e);
        const u16* xr = xin + e * 64           + cq * 16;
        const u16* ar = xin + (size_t)n.x * 64 + cq * 16;
        const u16* br = xin + (size_t)n.y * 64 + cq * 16;
        const u16* cr = xin + (size_t)n.z * 64 + cq * 16;
        const u16* dr = xin + (size_t)n.w * 64 + cq * 16;
        // issue all 10 independent loads up front
        const uint4 xv0 = *(const uint4*)(xr);     const uint4 xv1 = *(const uint4*)(xr + 8);
        const uint4 av0 = *(const uint4*)(ar);     const uint4 av1 = *(const uint4*)(ar + 8);
        const uint4 bv0 = *(const uint4*)(br);     const uint4 bv1 = *(const uint4*)(br + 8);
        const uint4 cv0 = *(const uint4*)(cr);     const uint4 cv1 = *(const uint4*)(cr + 8);
        const uint4 dv0 = *(const uint4*)(dr);     const uint4 dv1 = *(const uint4*)(dr + 8);
        const int mt    = el >> 5;
        const int lane0 = el & 31;
        u16* abase = afrag + (size_t)mt * (20 * 64 * 8);
        #pragma unroll
        for (int w8 = 0; w8 < 2; ++w8) {          // 8-ch windows of the quarter
            const uint4 xv = w8 ? xv1 : xv0;
            const uint4 av = w8 ? av1 : av0;
            const uint4 bv = w8 ? bv1 : bv0;
            const uint4 cv = w8 ? cv1 : cv0;
            const uint4 dv = w8 ? dv1 : dv0;
            const int ldst = lane0 + 32 * w8;
            uint4 g1, g2, g3, g4;
            const unsigned* ap = (const unsigned*)&av;
            const unsigned* bp = (const unsigned*)&bv;
            const unsigned* cp = (const unsigned*)&cv;
            const unsigned* dp = (const unsigned*)&dv;
            unsigned* g1p = (unsigned*)&g1; unsigned* g2p = (unsigned*)&g2;
            unsigned* g3p = (unsigned*)&g3; unsigned* g4p = (unsigned*)&g4;
            #pragma unroll
            for (int i = 0; i < 4; ++i) {
                const float a0 = lo2f(ap[i]), a1 = hi2f(ap[i]);
                const float c0 = lo2f(cp[i]), c1 = hi2f(cp[i]);
                g1p[i] = pk2(fabsf(a0 - c0), fabsf(a1 - c1));
                g2p[i] = pk2(a0 + c0, a1 + c1);
                const float b0 = lo2f(bp[i]), b1 = hi2f(bp[i]);
                const float d0 = lo2f(dp[i]), d1 = hi2f(dp[i]);
                g3p[i] = pk2(fabsf(b0 - d0), fabsf(b1 - d1));
                g4p[i] = pk2(b0 + d0, b1 + d1);
            }
            // group g -> kstep = g*4 + cq
            *(uint4*)(abase + (size_t)(((0*4 + cq) * 64) + ldst) * 8) = xv;
            *(uint4*)(abase + (size_t)(((1*4 + cq) * 64) + ldst) * 8) = g1;
            *(uint4*)(abase + (size_t)(((2*4 + cq) * 64) + ldst) * 8) = g2;
            *(uint4*)(abase + (size_t)(((3*4 + cq) * 64) + ldst) * 8) = g3;
            *(uint4*)(abase + (size_t)(((4*4 + cq) * 64) + ldst) * 8) = g4;
        }
    }
    __syncthreads();

    // ---- K-loop: 20 ksteps; A from LDS, B (own ntile) from global frags ----
    const int mt = wv >> 1, nt = wv & 1;
    f32x16 acc = {};
    const u16* ab = afrag + (size_t)mt * (20 * 64 * 8) + l * 8;
    const u16* bb = wf + (size_t)(nt * 64 + l) * 8;
    #pragma unroll
    for (int ks = 0; ks < 20; ++ks) {
        const bf16x8 a8 = *(const bf16x8*)(ab + ks * 512);
        const bf16x8 b8 = *(const bf16x8*)(bb + ks * 1024);
        acc = __builtin_amdgcn_mfma_f32_32x32x16_bf16(a8, b8, acc, 0, 0, 0);
    }
    __syncthreads();

    // ---- epilogue: C + bias -> ebuf [64][68] (aliases afrag) ----
    float* ebuf = (float*)afrag;
    {
        const int col  = nt * 32 + (l & 31);
        const int quad = l >> 5;
        const float bc = bias[col];
        #pragma unroll
        for (int r = 0; r < 16; ++r) {
            const int row = mt * 32 + (r & 3) + 8 * (r >> 2) + 4 * quad;
            ebuf[row * 68 + col] = acc[r] + bc;
        }
    }
    __syncthreads();

    // ---- LN + ReLU + residual -> bf16 store (4 threads/edge) ----
    {
        const int el = t >> 2, q = t & 3;
        const float* rp = ebuf + el * 68 + q * 16;
        float v[16];
        float s = 0.f, qs = 0.f;
        #pragma unroll
        for (int i = 0; i < 16; ++i) { v[i] = rp[i]; s += v[i]; qs += v[i] * v[i]; }
        s  += __shfl_xor(s, 1);  s  += __shfl_xor(s, 2);
        qs += __shfl_xor(qs, 1); qs += __shfl_xor(qs, 2);
        const float mu   = s * (1.f / 64.f);
        const float var  = qs * (1.f / 64.f) - mu * mu;
        const float rinv = rsqrtf(var + LN_EPS);
        const size_t e   = (size_t)(e0 + el);
        const u16* resp  = xin + e * 64 + q * 16;
        u16* outp        = xout + e * 64 + q * 16;
        #pragma unroll
        for (int h = 0; h < 2; ++h) {
            const uint4 res = *(const uint4*)(resp + h * 8);
            const unsigned* rr = (const unsigned*)&res;
            uint4 o; unsigned* op = (unsigned*)&o;
            #pragma unroll
            for (int i = 0; i < 4; ++i) {
                const int ci = q * 16 + h * 8 + i * 2;
                const float y0 = fmaxf(fmaf((v[h*8 + i*2]     - mu) * rinv, lng[ci],     lnb[ci]),     0.f) + lo2f(rr[i]);
                const float y1 = fmaxf(fmaf((v[h*8 + i*2 + 1] - mu) * rinv, lng[ci + 1], lnb[ci + 1]), 0.f) + hi2f(rr[i]);
                op[i] = pk2(y0, y1);
            }
            *(uint4*)(outp + h * 8) = o;
        }
    }
}

// ---------------------------------------------------------------------------
// Layer 0 (MFMA, K padded 55->64): feats(E x 55) @ w0 -> LN -> ReLU.
// x is fp32 E x 11. 2 threads/edge: h = t>>7 builds k-range [h*32, h*32+32).
// ---------------------------------------------------------------------------
__global__ __launch_bounds__(256) void layer0_mfma(
    const float* __restrict__ x, const int* __restrict__ nbr,
    const u16* __restrict__ wf0, const float* __restrict__ bias,
    const float* __restrict__ lng, const float* __restrict__ lnb,
    u16* __restrict__ xout)
{
    __shared__ float smem[128 * 68];          // 34.8 KB (afrag aliased: 16 KB)
    u16* afrag = (u16*)smem;
    const int t  = threadIdx.x;
    const int l  = t & 63;
    const int wv = t >> 6;
    const int e0 = blockIdx.x * 128;

    {
        const int el = t & 127;
        const int h  = t >> 7;                // wave-uniform
        const size_t e  = (size_t)(e0 + el);
        const size_t ec = e < E_EDGES ? e : (size_t)(E_EDGES - 1);
        const int4 n = *(const int4*)(nbr + 4 * ec);
        const float* xr = x + ec * 11;
        const float* ar = x + (size_t)n.x * 11;
        const float* br = x + (size_t)n.y * 11;
        const float* cr = x + (size_t)n.z * 11;
        const float* dr = x + (size_t)n.w * 11;
        float f[32];
        if (h == 0) {
            #pragma unroll
            for (int i = 0; i < 11; ++i) f[i] = xr[i];
            #pragma unroll
            for (int i = 0; i < 11; ++i) { const float a = ar[i], c = cr[i];
                f[11 + i] = fabsf(a - c); if (i < 10) f[22 + i] = a + c; }
        } else {
            f[0] = ar[10] + cr[10];                       // k = 32
            #pragma unroll
            for (int i = 0; i < 11; ++i) { const float b = br[i], d = dr[i];
                f[1 + i] = fabsf(b - d); f[12 + i] = b + d; }
            #pragma unroll
            for (int i = 23; i < 32; ++i) f[i] = 0.f;     // k 55..63 pad
        }
        const int mt    = el >> 5;
        const int lane0 = el & 31;
        u16* abase = afrag + (size_t)mt * (4 * 64 * 8);
        #pragma unroll
        for (int s8 = 0; s8 < 4; ++s8) {
            const int k0   = h * 32 + s8 * 8;
            const int ks   = k0 >> 4;
            const int half = (k0 >> 3) & 1;
            uint4 pk;
            pk.x = pk2(f[s8*8+0], f[s8*8+1]);
            pk.y = pk2(f[s8*8+2], f[s8*8+3]);
            pk.z = pk2(f[s8*8+4], f[s8*8+5]);
            pk.w = pk2(f[s8*8+6], f[s8*8+7]);
            *(uint4*)(abase + (size_t)(ks * 64 + lane0 + 32 * half) * 8) = pk;
        }
    }
    __syncthreads();

    f32x16 acc0 = {}, acc1 = {};
    const u16* ab = afrag + (size_t)wv * (4 * 64 * 8) + l * 8;
    #pragma unroll
    for (int ks = 0; ks < 4; ++ks) {
        const bf16x8 a8 = *(const bf16x8*)(ab + ks * 512);
        const bf16x8 b0 = *(const bf16x8*)(wf0 + (size_t)((ks*2    ) * 64 + l) * 8);
        const bf16x8 b1 = *(const bf16x8*)(wf0 + (size_t)((ks*2 + 1) * 64 + l) * 8);
        acc0 = __builtin_amdgcn_mfma_f32_32x32x16_bf16(a8, b0, acc0, 0, 0, 0);
        acc1 = __builtin_amdgcn_mfma_f32_32x32x16_bf16(a8, b1, acc1, 0, 0, 0);
    }
    __syncthreads();

    float* ebuf = smem;
    {
        const int col0 = l & 31;
        const int quad = l >> 5;
        const float bc0 = bias[col0];
        const float bc1 = bias[col0 + 32];
        #pragma unroll
        for (int r = 0; r < 16; ++r) {
            const int row = wv * 32 + (r & 3) + 8 * (r >> 2) + 4 * quad;
            ebuf[row * 68 + col0]      = acc0[r] + bc0;
            ebuf[row * 68 + col0 + 32] = acc1[r] + bc1;
        }
    }
    __syncthreads();

    {
        const int el = t >> 1, hf = t & 1;
        const float* rp = ebuf + el * 68 + hf * 32;
        float v[32];
        float s = 0.f, q = 0.f;
        #pragma unroll
        for (int i = 0; i < 32; ++i) { v[i] = rp[i]; s += v[i]; q += v[i] * v[i]; }
        s += __shfl_xor(s, 1); q += __shfl_xor(q, 1);
        const float mu   = s * (1.f / 64.f);
        const float var  = q * (1.f / 64.f) - mu * mu;
        const float rinv = rsqrtf(var + LN_EPS);
        const size_t e = (size_t)(e0 + el);
        if (e < E_EDGES) {
            u16* outp       = xout + e * 64 + hf * 32;
            const float* gp = lng + hf * 32;
            const float* bp = lnb + hf * 32;
            #pragma unroll
            for (int w8 = 0; w8 < 4; ++w8) {
                uint4 o; unsigned* op = (unsigned*)&o;
                #pragma unroll
                for (int i = 0; i < 4; ++i) {
                    const int ci = w8 * 8 + i * 2;
                    const float y0 = fmaxf(fmaf((v[ci]   - mu) * rinv, gp[ci],   bp[ci]),   0.f);
                    const float y1 = fmaxf(fmaf((v[ci+1] - mu) * rinv, gp[ci+1], bp[ci+1]), 0.f);
                    op[i] = pk2(y0, y1);
                }
                *(uint4*)(outp + w8 * 8) = o;
            }
        }
    }
}

// ---------------------------------------------------------------------------
// Head (MFMA): logits = relu(x @ cw1 + cb1) @ cw2 + cb2.
// Wave-per-32-edge tile, grid-stride; A straight from global, B in registers.
// ---------------------------------------------------------------------------
__global__ __launch_bounds__(256) void head_mfma(
    const u16* __restrict__ xin,
    const float* __restrict__ cw1, const float* __restrict__ cb1,
    const float* __restrict__ cw2, const float* __restrict__ cb2,
    float* __restrict__ out)
{
    const int t    = threadIdx.x;
    const int l    = t & 63;
    const int wv   = t >> 6;
    const int col  = l & 31;
    const int half = l >> 5;

    bf16x8 bf[4];
    #pragma unroll
    for (int ks = 0; ks < 4; ++ks) {
        const int kb = ks * 16 + half * 8;
        uint4 pk;
        pk.x = pk2(cw1[(kb+0)*32 + col], cw1[(kb+1)*32 + col]);
        pk.y = pk2(cw1[(kb+2)*32 + col], cw1[(kb+3)*32 + col]);
        pk.z = pk2(cw1[(kb+4)*32 + col], cw1[(kb+5)*32 + col]);
        pk.w = pk2(cw1[(kb+6)*32 + col], cw1[(kb+7)*32 + col]);
        __builtin_memcpy(&bf[ks], &pk, 16);
    }
    const float bc = cb1[col];
    const float w2 = cw2[col];
    const float b2 = cb2[0];

    const int nwaves = gridDim.x * 4;
    for (int tile = blockIdx.x * 4 + wv; tile < E_EDGES / 32; tile += nwaves) {
        const size_t e0 = (size_t)tile * 32;
        const u16* xb = xin + (e0 + col) * 64 + half * 8;
        f32x16 acc = {};
        #pragma unroll
        for (int ks = 0; ks < 4; ++ks) {
            const bf16x8 a8 = *(const bf16x8*)(xb + ks * 16);
            acc = __builtin_amdgcn_mfma_f32_32x32x16_bf16(a8, bf[ks], acc, 0, 0, 0);
        }
        float sums[16];
        #pragma unroll
        for (int r = 0; r < 16; ++r) {
            float z = fmaxf(acc[r] + bc, 0.f) * w2;
            z += __shfl_xor(z, 1); z += __shfl_xor(z, 2); z += __shfl_xor(z, 4);
            z += __shfl_xor(z, 8); z += __shfl_xor(z, 16);
            sums[r] = z;
        }
        if (col == 0) {
            #pragma unroll
            for (int r = 0; r < 16; ++r) {
                const int row = (r & 3) + 8 * (r >> 2) + 4 * half;
                out[e0 + row] = sums[r] + b2;
            }
        }
    }
}

// ---------------------------------------------------------------------------
extern "C" void kernel_launch(void* const* d_in, const int* in_sizes, int n_in,
                              void* d_out, int out_size, void* d_ws, size_t ws_size,
                              hipStream_t stream)
{
    (void)in_sizes; (void)n_in; (void)out_size; (void)ws_size;
    const float* x   = (const float*)d_in[0];
    const int*   nbr = (const int*)d_in[1];
    const float* w0  = (const float*)d_in[2];
    const float* b0  = (const float*)d_in[3];
    const float* wr  = (const float*)d_in[4];
    const float* br  = (const float*)d_in[5];
    const float* lg  = (const float*)d_in[6];
    const float* lb  = (const float*)d_in[7];
    const float* cw1 = (const float*)d_in[8];
    const float* cb1 = (const float*)d_in[9];
    const float* cw2 = (const float*)d_in[10];
    const float* cb2 = (const float*)d_in[11];
    float* out = (float*)d_out;

    u16* xa = (u16*)d_ws;                       // E x 64 bf16 (128 MB)
    u16* xb = xa + (size_t)E_EDGES * 64;        // E x 64 bf16 (128 MB)
    u16* wfrag = (u16*)d_out;                   // 128 KB scratch; head overwrites d_out

    const dim3 blk(256);

    wconv_kernel<<<dim3(32), blk, 0, stream>>>(wr, w0, wfrag);
    layer0_mfma<<<dim3((E_EDGES + 127) / 128), blk, 0, stream>>>(x, nbr, wfrag + 3*20480, b0, lg, lb, xa);
    layer_mfma<<<dim3(E_EDGES / 64), blk, 0, stream>>>(xa, nbr, wfrag,           br,        lg + 64,  lb + 64,  xb);
    layer_mfma<<<dim3(E_EDGES / 64), blk, 0, stream>>>(xb, nbr, wfrag + 20480,   br + 64,   lg + 128, lb + 128, xa);
    layer_mfma<<<dim3(E_EDGES / 64), blk, 0, stream>>>(xa, nbr, wfrag + 40960,   br + 128,  lg + 192, lb + 192, xb);
    head_mfma<<<dim3(2048), blk, 0, stream>>>(xb, cw1, cb1, cw2, cb2, out);
}

// Round 6
// 684.289 us; speedup vs baseline: 4.7098x; 1.0159x over previous
//
#include <hip/hip_runtime.h>
#include <hip/hip_bf16.h>
#include <math.h>

#define E_EDGES 1000000
#define LN_EPS  1e-5f

typedef unsigned short u16;
typedef __bf16 bf16x8 __attribute__((ext_vector_type(8)));
typedef float  f32x16 __attribute__((ext_vector_type(16)));

__device__ __forceinline__ float lo2f(unsigned d) {
    union { unsigned u; float f; } v; v.u = d << 16; return v.f;
}
__device__ __forceinline__ float hi2f(unsigned d) {
    union { unsigned u; float f; } v; v.u = d & 0xffff0000u; return v.f;
}
__device__ __forceinline__ unsigned pk2(float lo, float hi) {
    __hip_bfloat162 h = __float22bfloat162_rn(make_float2(lo, hi));
    unsigned r; __builtin_memcpy(&r, &h, 4); return r;
}

// ---------------------------------------------------------------------------
// Weight -> bf16 MFMA B-fragment conversion (one-time, ~128 KB in d_out;
// head_mfma overwrites d_out afterwards).
// slot s = (ks*2+nt)*64 + l holds B[k=ks*16+(l>>5)*8+j][n=nt*32+(l&31)].
// ---------------------------------------------------------------------------
__global__ __launch_bounds__(256) void wconv_kernel(
    const float* __restrict__ wr, const float* __restrict__ w0,
    u16* __restrict__ wf)
{
    const int s = blockIdx.x * 256 + threadIdx.x;   // 0..8191
    const int l    = s & 63;
    const int nt   = (s >> 6) & 1;
    const int col  = nt * 32 + (l & 31);
    const int half = l >> 5;
    uint4 pk;
    if (s < 3 * 2560) {
        const int L  = s / 2560;
        const int sl = s % 2560;
        const int kb = (sl >> 7) * 16 + half * 8;
        const float* W = wr + L * 320 * 64;
        pk.x = pk2(W[(kb+0)*64+col], W[(kb+1)*64+col]);
        pk.y = pk2(W[(kb+2)*64+col], W[(kb+3)*64+col]);
        pk.z = pk2(W[(kb+4)*64+col], W[(kb+5)*64+col]);
        pk.w = pk2(W[(kb+6)*64+col], W[(kb+7)*64+col]);
    } else {
        const int sl = s - 3 * 2560;
        const int kb = (sl >> 7) * 16 + half * 8;
        float v[8];
        #pragma unroll
        for (int p = 0; p < 8; ++p) v[p] = (kb + p < 55) ? w0[(kb+p)*64 + col] : 0.f;
        pk.x = pk2(v[0],v[1]); pk.y = pk2(v[2],v[3]);
        pk.z = pk2(v[4],v[5]); pk.w = pk2(v[6],v[7]);
    }
    *(uint4*)&wf[(size_t)s * 8] = pk;
}

// ---------------------------------------------------------------------------
// Layers 1..3: feats(E x 320) @ W + b -> LN -> ReLU -> +residual.
// 64 edges/block, 4 waves = (mt,nt). afrag 40 KB -> 4 blocks/CU (16 waves:
// the LDS-imposed cap: 20 KB of A per 32-edge wave-pair x 8 pairs = 160 KB).
// Bank swizzle: granule ^= (row&3) in both write and read (we own layout).
// Residual kept in registers (xv0/xv1) across the K-loop.
// ---------------------------------------------------------------------------
__global__ __launch_bounds__(256, 4) void layer_mfma(
    const u16* __restrict__ xin, const int* __restrict__ nbr,
    const u16* __restrict__ wf, const float* __restrict__ bias,
    const float* __restrict__ lng, const float* __restrict__ lnb,
    u16* __restrict__ xout)
{
    __shared__ u16 afrag[2 * 20 * 64 * 8];   // 40 KB
    const int t  = threadIdx.x;
    const int l  = t & 63;
    const int wv = t >> 6;
    const int e0 = blockIdx.x * 64;          // grid exact: 15625*64 = 1e6
    const int el = t >> 2;                   // 0..63 local edge
    const int cq = t & 3;                    // 16-ch quarter

    uint4 xv0, xv1;                          // own row: features + residual
    {
        const size_t e = (size_t)(e0 + el);
        const int4 n = *(const int4*)(nbr + 4 * e);
        const u16* xr = xin + e * 64           + cq * 16;
        const u16* ar = xin + (size_t)n.x * 64 + cq * 16;
        const u16* br = xin + (size_t)n.y * 64 + cq * 16;
        const u16* cr = xin + (size_t)n.z * 64 + cq * 16;
        const u16* dr = xin + (size_t)n.w * 64 + cq * 16;
        xv0 = *(const uint4*)(xr);                 xv1 = *(const uint4*)(xr + 8);
        const uint4 av0 = *(const uint4*)(ar);     const uint4 av1 = *(const uint4*)(ar + 8);
        const uint4 bv0 = *(const uint4*)(br);     const uint4 bv1 = *(const uint4*)(br + 8);
        const uint4 cv0 = *(const uint4*)(cr);     const uint4 cv1 = *(const uint4*)(cr + 8);
        const uint4 dv0 = *(const uint4*)(dr);     const uint4 dv1 = *(const uint4*)(dr + 8);
        const int mt_g  = el >> 5;
        const int lane0 = el & 31;
        u16* abase = afrag + (size_t)mt_g * (20 * 64 * 8);
        #pragma unroll
        for (int w8 = 0; w8 < 2; ++w8) {
            const uint4 xv = w8 ? xv1 : xv0;
            const uint4 av = w8 ? av1 : av0;
            const uint4 bv = w8 ? bv1 : bv0;
            const uint4 cv = w8 ? cv1 : cv0;
            const uint4 dv = w8 ? dv1 : dv0;
            const int gsw = (lane0 + 32 * w8) ^ cq;   // bank swizzle
            uint4 g1, g2, g3, g4;
            const unsigned* ap = (const unsigned*)&av;
            const unsigned* bp = (const unsigned*)&bv;
            const unsigned* cp = (const unsigned*)&cv;
            const unsigned* dp = (const unsigned*)&dv;
            unsigned* g1p = (unsigned*)&g1; unsigned* g2p = (unsigned*)&g2;
            unsigned* g3p = (unsigned*)&g3; unsigned* g4p = (unsigned*)&g4;
            #pragma unroll
            for (int i = 0; i < 4; ++i) {
                const float a0 = lo2f(ap[i]), a1 = hi2f(ap[i]);
                const float c0 = lo2f(cp[i]), c1 = hi2f(cp[i]);
                g1p[i] = pk2(a0 - c0, a1 - c1) & 0x7FFF7FFFu;   // |RNE(x)|=RNE(|x|)
                g2p[i] = pk2(a0 + c0, a1 + c1);
                const float b0 = lo2f(bp[i]), b1 = hi2f(bp[i]);
                const float d0 = lo2f(dp[i]), d1 = hi2f(dp[i]);
                g3p[i] = pk2(b0 - d0, b1 - d1) & 0x7FFF7FFFu;
                g4p[i] = pk2(b0 + d0, b1 + d1);
            }
            // group g -> row (kstep) = g*4 + cq; row&3 == cq matches read swizzle
            *(uint4*)(abase + (size_t)(((0*4 + cq) * 64) + gsw) * 8) = xv;
            *(uint4*)(abase + (size_t)(((1*4 + cq) * 64) + gsw) * 8) = g1;
            *(uint4*)(abase + (size_t)(((2*4 + cq) * 64) + gsw) * 8) = g2;
            *(uint4*)(abase + (size_t)(((3*4 + cq) * 64) + gsw) * 8) = g3;
            *(uint4*)(abase + (size_t)(((4*4 + cq) * 64) + gsw) * 8) = g4;
        }
    }
    __syncthreads();

    // ---- K-loop: 20 ksteps; A from LDS (swizzled), B from global frags ----
    const int mt = wv >> 1, nt = wv & 1;
    f32x16 acc = {};
    const u16* ab = afrag + (size_t)mt * (20 * 512);
    const u16* bb = wf + (size_t)(nt * 64 + l) * 8;
    #pragma unroll
    for (int ks = 0; ks < 20; ++ks) {
        const bf16x8 a8 = *(const bf16x8*)(ab + (size_t)(ks * 64 + (l ^ (ks & 3))) * 8);
        const bf16x8 b8 = *(const bf16x8*)(bb + ks * 1024);
        acc = __builtin_amdgcn_mfma_f32_32x32x16_bf16(a8, b8, acc, 0, 0, 0);
    }
    __syncthreads();

    // ---- epilogue: C + bias -> ebuf [64][68] (aliases afrag) ----
    float* ebuf = (float*)afrag;
    {
        const int col  = nt * 32 + (l & 31);
        const int quad = l >> 5;
        const float bc = bias[col];
        #pragma unroll
        for (int r = 0; r < 16; ++r) {
            const int row = mt * 32 + (r & 3) + 8 * (r >> 2) + 4 * quad;
            ebuf[row * 68 + col] = acc[r] + bc;
        }
    }
    __syncthreads();

    // ---- LN + ReLU + residual(from regs) -> bf16 store (4 threads/edge) ----
    {
        const float* rp = ebuf + el * 68 + cq * 16;
        float v[16];
        float s = 0.f, qs = 0.f;
        #pragma unroll
        for (int i = 0; i < 16; ++i) { v[i] = rp[i]; s += v[i]; qs += v[i] * v[i]; }
        s  += __shfl_xor(s, 1);  s  += __shfl_xor(s, 2);
        qs += __shfl_xor(qs, 1); qs += __shfl_xor(qs, 2);
        const float mu   = s * (1.f / 64.f);
        const float var  = qs * (1.f / 64.f) - mu * mu;
        const float rinv = rsqrtf(var + LN_EPS);
        const size_t e   = (size_t)(e0 + el);
        u16* outp        = xout + e * 64 + cq * 16;
        #pragma unroll
        for (int h = 0; h < 2; ++h) {
            const uint4 res = h ? xv1 : xv0;           // residual from registers
            const unsigned* rr = (const unsigned*)&res;
            uint4 o; unsigned* op = (unsigned*)&o;
            #pragma unroll
            for (int i = 0; i < 4; ++i) {
                const int ci = cq * 16 + h * 8 + i * 2;
                const float y0 = fmaxf(fmaf((v[h*8 + i*2]     - mu) * rinv, lng[ci],     lnb[ci]),     0.f) + lo2f(rr[i]);
                const float y1 = fmaxf(fmaf((v[h*8 + i*2 + 1] - mu) * rinv, lng[ci + 1], lnb[ci + 1]), 0.f) + hi2f(rr[i]);
                op[i] = pk2(y0, y1);
            }
            *(uint4*)(outp + h * 8) = o;
        }
    }
}

// ---------------------------------------------------------------------------
// Layer 0 (MFMA, K padded 55->64): 64 edges/block, 4 waves, 17.4 KB LDS.
// Thread (el, cq) builds k-range [cq*16, cq*16+16) of the concat features.
// ---------------------------------------------------------------------------
__global__ __launch_bounds__(256, 6) void layer0_mfma(
    const float* __restrict__ x, const int* __restrict__ nbr,
    const u16* __restrict__ wf0, const float* __restrict__ bias,
    const float* __restrict__ lng, const float* __restrict__ lnb,
    u16* __restrict__ xout)
{
    __shared__ float smem[64 * 68];          // 17.4 KB; first 8 KB doubles as afrag
    u16* afrag = (u16*)smem;
    const int t  = threadIdx.x;
    const int l  = t & 63;
    const int wv = t >> 6;
    const int e0 = blockIdx.x * 64;          // grid exact: 15625
    const int el = t >> 2, cq = t & 3;

    {
        const size_t e = (size_t)(e0 + el);
        const int4 n = *(const int4*)(nbr + 4 * e);
        const float* xr = x + e * 11;
        const float* ar = x + (size_t)n.x * 11;
        const float* br = x + (size_t)n.y * 11;
        const float* cr = x + (size_t)n.z * 11;
        const float* dr = x + (size_t)n.w * 11;
        float f[16];
        if (cq == 0) {            // k 0..10: x ; k 11..15: |a-c|[0..4]
            #pragma unroll
            for (int i = 0; i < 11; ++i) f[i] = xr[i];
            #pragma unroll
            for (int i = 0; i < 5; ++i) f[11 + i] = fabsf(ar[i] - cr[i]);
        } else if (cq == 1) {     // k 16..21: |a-c|[5..10] ; k 22..31: a+c[0..9]
            #pragma unroll
            for (int i = 0; i < 6; ++i) f[i] = fabsf(ar[5 + i] - cr[5 + i]);
            #pragma unroll
            for (int i = 0; i < 10; ++i) f[6 + i] = ar[i] + cr[i];
        } else if (cq == 2) {     // k32: a+c[10]; k33..43: |b-d|; k44..47: b+d[0..3]
            f[0] = ar[10] + cr[10];
            #pragma unroll
            for (int i = 0; i < 11; ++i) f[1 + i] = fabsf(br[i] - dr[i]);
            #pragma unroll
            for (int i = 0; i < 4; ++i) f[12 + i] = br[i] + dr[i];
        } else {                  // k48..54: b+d[4..10]; k55..63: pad 0
            #pragma unroll
            for (int i = 0; i < 7; ++i) f[i] = br[4 + i] + dr[4 + i];
            #pragma unroll
            for (int i = 7; i < 16; ++i) f[i] = 0.f;
        }
        const int mt_g  = el >> 5;
        const int lane0 = el & 31;
        u16* abase = afrag + (size_t)mt_g * (4 * 64 * 8);
        #pragma unroll
        for (int hh = 0; hh < 2; ++hh) {
            uint4 pk;
            pk.x = pk2(f[hh*8+0], f[hh*8+1]);
            pk.y = pk2(f[hh*8+2], f[hh*8+3]);
            pk.z = pk2(f[hh*8+4], f[hh*8+5]);
            pk.w = pk2(f[hh*8+6], f[hh*8+7]);
            const int gsw = (lane0 + 32 * hh) ^ cq;   // row (=cq) bank swizzle
            *(uint4*)(abase + (size_t)(cq * 64 + gsw) * 8) = pk;
        }
    }
    __syncthreads();

    const int mt = wv >> 1, nt = wv & 1;
    f32x16 acc = {};
    const u16* ab = afrag + (size_t)mt * (4 * 512);
    const u16* bb = wf0 + (size_t)(nt * 64 + l) * 8;
    #pragma unroll
    for (int ks = 0; ks < 4; ++ks) {
        const bf16x8 a8 = *(const bf16x8*)(ab + (size_t)(ks * 64 + (l ^ ks)) * 8);
        const bf16x8 b8 = *(const bf16x8*)(bb + ks * 1024);
        acc = __builtin_amdgcn_mfma_f32_32x32x16_bf16(a8, b8, acc, 0, 0, 0);
    }
    __syncthreads();

    float* ebuf = smem;
    {
        const int col  = nt * 32 + (l & 31);
        const int quad = l >> 5;
        const float bc = bias[col];
        #pragma unroll
        for (int r = 0; r < 16; ++r) {
            const int row = mt * 32 + (r & 3) + 8 * (r >> 2) + 4 * quad;
            ebuf[row * 68 + col] = acc[r] + bc;
        }
    }
    __syncthreads();

    {
        const float* rp = ebuf + el * 68 + cq * 16;
        float v[16];
        float s = 0.f, qs = 0.f;
        #pragma unroll
        for (int i = 0; i < 16; ++i) { v[i] = rp[i]; s += v[i]; qs += v[i] * v[i]; }
        s  += __shfl_xor(s, 1);  s  += __shfl_xor(s, 2);
        qs += __shfl_xor(qs, 1); qs += __shfl_xor(qs, 2);
        const float mu   = s * (1.f / 64.f);
        const float var  = qs * (1.f / 64.f) - mu * mu;
        const float rinv = rsqrtf(var + LN_EPS);
        const size_t e   = (size_t)(e0 + el);
        u16* outp        = xout + e * 64 + cq * 16;
        #pragma unroll
        for (int h = 0; h < 2; ++h) {
            uint4 o; unsigned* op = (unsigned*)&o;
            #pragma unroll
            for (int i = 0; i < 4; ++i) {
                const int ci = cq * 16 + h * 8 + i * 2;
                const float y0 = fmaxf(fmaf((v[h*8 + i*2]     - mu) * rinv, lng[ci],     lnb[ci]),     0.f);
                const float y1 = fmaxf(fmaf((v[h*8 + i*2 + 1] - mu) * rinv, lng[ci + 1], lnb[ci + 1]), 0.f);
                op[i] = pk2(y0, y1);
            }
            *(uint4*)(outp + h * 8) = o;
        }
    }
}

// ---------------------------------------------------------------------------
// Head (MFMA): logits = relu(x @ cw1 + cb1) @ cw2 + cb2.
// One 32-edge tile per wave; row-sum via per-wave LDS transpose (16 writes +
// 16 reads + 1 shfl) instead of 80 ds_bpermute butterflies.
// ---------------------------------------------------------------------------
__global__ __launch_bounds__(256) void head_mfma(
    const u16* __restrict__ xin,
    const float* __restrict__ cw1, const float* __restrict__ cb1,
    const float* __restrict__ cw2, const float* __restrict__ cb2,
    float* __restrict__ out)
{
    __shared__ float hbuf[4][32 * 33];   // 16.9 KB, per-wave private region
    const int t    = threadIdx.x;
    const int l    = t & 63;
    const int wv   = t >> 6;
    const int col  = l & 31;
    const int half = l >> 5;

    bf16x8 bf[4];
    #pragma unroll
    for (int ks = 0; ks < 4; ++ks) {
        const int kb = ks * 16 + half * 8;
        uint4 pk;
        pk.x = pk2(cw1[(kb+0)*32 + col], cw1[(kb+1)*32 + col]);
        pk.y = pk2(cw1[(kb+2)*32 + col], cw1[(kb+3)*32 + col]);
        pk.z = pk2(cw1[(kb+4)*32 + col], cw1[(kb+5)*32 + col]);
        pk.w = pk2(cw1[(kb+6)*32 + col], cw1[(kb+7)*32 + col]);
        __builtin_memcpy(&bf[ks], &pk, 16);
    }
    const float bc = cb1[col];
    const float w2 = cw2[col];
    const float b2 = cb2[0];

    int tile = blockIdx.x * 4 + wv;
    const int valid = tile < (E_EDGES / 32);
    if (!valid) tile = E_EDGES / 32 - 1;           // clamp: keep loads in-bounds
    const size_t e0 = (size_t)tile * 32;
    const u16* xb = xin + (e0 + col) * 64 + half * 8;
    f32x16 acc = {};
    #pragma unroll
    for (int ks = 0; ks < 4; ++ks) {
        const bf16x8 a8 = *(const bf16x8*)(xb + ks * 16);
        acc = __builtin_amdgcn_mfma_f32_32x32x16_bf16(a8, bf[ks], acc, 0, 0, 0);
    }
    float* hb = hbuf[wv];
    #pragma unroll
    for (int r = 0; r < 16; ++r) {
        const int row = (r & 3) + 8 * (r >> 2) + 4 * half;
        hb[row * 33 + col] = fmaxf(acc[r] + bc, 0.f) * w2;
    }
    __syncthreads();                               // uniform (clamped waves too)
    const int row2 = l >> 1, part = l & 1;
    const float* rp = hb + row2 * 33 + part * 16;
    float s = 0.f;
    #pragma unroll
    for (int i = 0; i < 16; ++i) s += rp[i];
    s += __shfl_xor(s, 1);
    if (valid && part == 0) out[e0 + row2] = s + b2;
}

// ---------------------------------------------------------------------------
extern "C" void kernel_launch(void* const* d_in, const int* in_sizes, int n_in,
                              void* d_out, int out_size, void* d_ws, size_t ws_size,
                              hipStream_t stream)
{
    (void)in_sizes; (void)n_in; (void)out_size; (void)ws_size;
    const float* x   = (const float*)d_in[0];
    const int*   nbr = (const int*)d_in[1];
    const float* w0  = (const float*)d_in[2];
    const float* b0  = (const float*)d_in[3];
    const float* wr  = (const float*)d_in[4];
    const float* br  = (const float*)d_in[5];
    const float* lg  = (const float*)d_in[6];
    const float* lb  = (const float*)d_in[7];
    const float* cw1 = (const float*)d_in[8];
    const float* cb1 = (const float*)d_in[9];
    const float* cw2 = (const float*)d_in[10];
    const float* cb2 = (const float*)d_in[11];
    float* out = (float*)d_out;

    u16* xa = (u16*)d_ws;                       // E x 64 bf16 (128 MB)
    u16* xb = xa + (size_t)E_EDGES * 64;        // E x 64 bf16 (128 MB)
    u16* wfrag = (u16*)d_out;                   // 128 KB scratch; head overwrites d_out

    const dim3 blk(256);

    wconv_kernel<<<dim3(32), blk, 0, stream>>>(wr, w0, wfrag);
    layer0_mfma<<<dim3(E_EDGES / 64), blk, 0, stream>>>(x, nbr, wfrag + 3*20480, b0, lg, lb, xa);
    layer_mfma<<<dim3(E_EDGES / 64), blk, 0, stream>>>(xa, nbr, wfrag,           br,        lg + 64,  lb + 64,  xb);
    layer_mfma<<<dim3(E_EDGES / 64), blk, 0, stream>>>(xb, nbr, wfrag + 20480,   br + 64,   lg + 128, lb + 128, xa);
    layer_mfma<<<dim3(E_EDGES / 64), blk, 0, stream>>>(xa, nbr, wfrag + 40960,   br + 128,  lg + 192, lb + 192, xb);
    head_mfma<<<dim3((E_EDGES / 32 + 3) / 4), blk, 0, stream>>>(xb, cw1, cb1, cw2, cb2, out);
}